// Round 11
// baseline (146.314 us; speedup 1.0000x reference)
//
#include <hip/hip_runtime.h>

typedef short s16x4 __attribute__((ext_vector_type(4)));
typedef short s16x8 __attribute__((ext_vector_type(8)));
typedef float f32x2 __attribute__((ext_vector_type(2)));
typedef float f32x16 __attribute__((ext_vector_type(16)));
typedef unsigned int u32x4 __attribute__((ext_vector_type(4)));

#define HT_STRIDE 72      // bf16 row stride: 144 B = 9*16 -> aligned b128 rows
#define CHUNK_ELEMS 8192  // 16 KB: 2 o-tiles x 2 jt x 4 ks x 64 lanes x 8 bf16

__device__ __forceinline__ unsigned short f2bf(float f) {
    unsigned int u = __float_as_uint(f);
    u += 0x7fffu + ((u >> 16) & 1u);
    return (unsigned short)(u >> 16);
}
__device__ __forceinline__ float bf2f(unsigned short h) {
    return __uint_as_float(((unsigned int)h) << 16);
}
__device__ __forceinline__ unsigned int pk2bf_rne(float lo, float hi) {
    unsigned int a = __float_as_uint(lo);
    a += 0x7fffu + ((a >> 16) & 1u);
    unsigned int b = __float_as_uint(hi);
    b += 0x7fffu + ((b >> 16) & 1u);
    return (a >> 16) | (b & 0xffff0000u);
}

// Factorization: T_l[(o,j),d] = sum_i W_l[o, i*64+j] * x[i,d]  (GEMM, K=i=64)
// A-frag layout, chunk-contiguous: slice G = ((l*64 + o)*2 + jt)*4 + ks
//   Wp[G*512 + lane*8 + t] = bf16( W_l[o][ (16*ks + 8*(lane>>5) + t)*64 + jt*32 + (lane&31) ] )
// One chunk = 2 consecutive o (16 KB) = exactly what one block stages per iter.
__global__ __launch_bounds__(256) void prepack_kernel(const float* __restrict__ W1,
                                                      const float* __restrict__ W2,
                                                      unsigned short* __restrict__ Wp) {
    __shared__ float sRow[4096]; // one W row, 16 KB
    const int blk = blockIdx.x;  // 0..127
    const int l = blk >> 6, o = blk & 63;
    const float* W = l ? W2 : W1;
    const float4* src = (const float4*)(W + o * 4096);
    float4* dstL = (float4*)sRow;
#pragma unroll
    for (int r = 0; r < 4; ++r)
        dstL[r * 256 + threadIdx.x] = src[r * 256 + threadIdx.x];
    __syncthreads();
#pragma unroll
    for (int s = 0; s < 2; ++s) {
        int sl = s * 256 + threadIdx.x; // 0..511 <-> (jt, ks, lane)
        int lane = sl & 63;
        int ks = (sl >> 6) & 3;
        int jt = sl >> 8;
        int q2 = lane >> 5, n31 = lane & 31;
        const float* base = sRow + jt * 32 + n31;
        int i0 = 16 * ks + 8 * q2;
        u32x4 pv;
        pv[0] = pk2bf_rne(base[(i0 + 0) * 64], base[(i0 + 1) * 64]);
        pv[1] = pk2bf_rne(base[(i0 + 2) * 64], base[(i0 + 3) * 64]);
        pv[2] = pk2bf_rne(base[(i0 + 4) * 64], base[(i0 + 5) * 64]);
        pv[3] = pk2bf_rne(base[(i0 + 6) * 64], base[(i0 + 7) * 64]);
        int G = ((l * 64 + o) * 2 + jt) * 4 + ks;
        ((u32x4*)Wp)[G * 64 + lane] = pv;
    }
}

// async stage of one 16 KB chunk across 4 waves (layouts match exactly ->
// wave-uniform base + lane*16, the global_load_lds requirement)
__device__ __forceinline__ void stage_chunk(const unsigned short* g, unsigned short* s,
                                            int w, int lane) {
#pragma unroll
    for (int r = 0; r < 4; ++r) {
        const unsigned short* gp = g + w * 2048 + r * 512 + lane * 8;
        unsigned short* lp = s + w * 2048 + r * 512;
        __builtin_amdgcn_global_load_lds(
            (const __attribute__((address_space(1))) unsigned int*)gp,
            (__attribute__((address_space(3))) unsigned int*)lp,
            16, 0, 0);
    }
}

// Block = 2 batch elems, 4 waves: wave = (nt = w&1 d-half, oh2 = w>>1 o-parity).
// Each wave handles BOTH b's -> every A-frag ds_read feeds 2 MFMAs.
// W staged to LDS once per block (async dbuf, 1 barrier/chunk): L2 traffic
// halves vs round 9/10 and A-path latency moves to LDS where the compiler's
// fine-grained lgkmcnt scheduling hides it.
__global__ __launch_bounds__(256, 2) void cin_kernel(const float* __restrict__ x,
                                                     const unsigned short* __restrict__ Wp,
                                                     const float* __restrict__ b1,
                                                     const float* __restrict__ b2,
                                                     const float* __restrict__ Wfc,
                                                     const float* __restrict__ bfc,
                                                     float* __restrict__ out) {
    __shared__ __align__(16) unsigned short sW[2 * CHUNK_ELEMS];   // 32 KB dbuf
    // sH[b]: x during layer 0 setup; overwritten in-place by h1 (x is dead
    // once bfr/cw are in registers)
    __shared__ __align__(16) unsigned short sH[2][64 * HT_STRIDE]; // 18.4 KB
    __shared__ float sBias[128], sWfc[128], sRed[4][2];

    const int tid = threadIdx.x;
    const int w = tid >> 6;
    const int lane = tid & 63;
    const int q2 = lane >> 5;
    const int n31 = lane & 31;
    const int nt = w & 1;   // d-half
    const int oh2 = w >> 1; // o-parity
    const int d = nt * 32 + n31;
    const int bb = blockIdx.x;

    // ---- stage x for both b's: coalesced float4 -> transposed bf16 LDS ----
#pragma unroll
    for (int bl = 0; bl < 2; ++bl) {
        const float4* xb4 = (const float4*)(x + (bb * 2 + bl) * 4096);
#pragma unroll
        for (int rr = 0; rr < 4; ++rr) {
            int e4 = rr * 256 + tid;
            float4 v = xb4[e4];
            int e = e4 << 2;
            int f = e >> 6;   // field index (i / j)
            int d0 = e & 63;  // d-index (multiple of 4)
            sH[bl][(d0 + 0) * HT_STRIDE + f] = f2bf(v.x);
            sH[bl][(d0 + 1) * HT_STRIDE + f] = f2bf(v.y);
            sH[bl][(d0 + 2) * HT_STRIDE + f] = f2bf(v.z);
            sH[bl][(d0 + 3) * HT_STRIDE + f] = f2bf(v.w);
        }
    }
    if (tid < 128) {
        sBias[tid] = (tid < 64) ? b1[tid] : b2[tid - 64];
        sWfc[tid] = Wfc[tid];
    }
    stage_chunk(Wp, sW, w, lane); // chunk 0 -> buf 0 (async)
    __syncthreads();

    const f32x16 zz = {};
    float contrib0 = 0.0f, contrib1 = 0.0f;

    // ---- MFMA B-frags: B[k=i][n=d] = x[i,d] — fixed for BOTH layers ----
    s16x8 bfr[2][4]; // [b][ks]
#pragma unroll
    for (int b = 0; b < 2; ++b)
#pragma unroll
        for (int ks = 0; ks < 4; ++ks)
            bfr[b][ks] = *(const s16x8*)&sH[b][d * HT_STRIDE + 16 * ks + 8 * q2];

    // ---- consume weights (j-factor), unpacked f32, reloaded at layer 1 ----
    f32x2 cw[2][2][8]; // [b][jt][pair], acc regs r=2p,2p+1
    auto load_cw = [&]() {
#pragma unroll
        for (int b = 0; b < 2; ++b)
#pragma unroll
            for (int jt = 0; jt < 2; ++jt)
#pragma unroll
                for (int m = 0; m < 4; ++m) {
                    s16x4 hv = *(const s16x4*)&sH[b][d * HT_STRIDE + jt * 32 + 4 * q2 + 8 * m];
                    cw[b][jt][2 * m] = (f32x2){bf2f((unsigned short)hv[0]),
                                               bf2f((unsigned short)hv[1])};
                    cw[b][jt][2 * m + 1] = (f32x2){bf2f((unsigned short)hv[2]),
                                                   bf2f((unsigned short)hv[3])};
                }
    };
    load_cw();

#pragma unroll 2
    for (int c = 0; c < 64; ++c) {
        __syncthreads(); // stage(c) complete; buf[(c+1)&1] readers done
        if (c < 63) stage_chunk(Wp + (c + 1) * CHUNK_ELEMS,
                                sW + ((c + 1) & 1) * CHUNK_ELEMS, w, lane);
        if (c == 32) load_cw(); // sH now holds h1 (all writes pre-barrier)

        const int l = c >> 5;
        const int o = ((c & 31) << 1) + oh2;
        const unsigned short* sA = sW + (c & 1) * CHUNK_ELEMS + oh2 * 4096;
        f32x2 hp[2];

#pragma unroll
        for (int jt = 0; jt < 2; ++jt) {
            const s16x8* Ap = (const s16x8*)(sA + jt * 2048) + lane;
            s16x8 A0 = Ap[0], A1 = Ap[64], A2 = Ap[128], A3 = Ap[192];
            f32x16 a0 = __builtin_amdgcn_mfma_f32_32x32x16_bf16(A0, bfr[0][0], zz, 0, 0, 0);
            f32x16 a1 = __builtin_amdgcn_mfma_f32_32x32x16_bf16(A0, bfr[1][0], zz, 0, 0, 0);
            a0 = __builtin_amdgcn_mfma_f32_32x32x16_bf16(A1, bfr[0][1], a0, 0, 0, 0);
            a1 = __builtin_amdgcn_mfma_f32_32x32x16_bf16(A1, bfr[1][1], a1, 0, 0, 0);
            a0 = __builtin_amdgcn_mfma_f32_32x32x16_bf16(A2, bfr[0][2], a0, 0, 0, 0);
            a1 = __builtin_amdgcn_mfma_f32_32x32x16_bf16(A2, bfr[1][2], a1, 0, 0, 0);
            a0 = __builtin_amdgcn_mfma_f32_32x32x16_bf16(A3, bfr[0][3], a0, 0, 0, 0);
            a1 = __builtin_amdgcn_mfma_f32_32x32x16_bf16(A3, bfr[1][3], a1, 0, 0, 0);

            // consume T-tile: weighted column-sum over its 32 j-rows
#pragma unroll
            for (int b = 0; b < 2; ++b) {
                const f32x2* a2 = b ? (const f32x2*)&a1 : (const f32x2*)&a0;
                f32x2 s = a2[0] * cw[b][jt][0];
#pragma unroll
                for (int p = 1; p < 8; ++p) s += a2[p] * cw[b][jt][p];
                if (jt == 0) {
                    hp[b] = s;
                } else {
                    f32x2 t2 = hp[b] + s;
                    float hsum = t2.x + t2.y;
                    hsum += __shfl_xor(hsum, 32, 64); // partner q2-half rows
                    float v = fmaxf(hsum + sBias[l * 64 + o], 0.0f);
                    if (b) contrib1 += v * sWfc[l * 64 + o];
                    else   contrib0 += v * sWfc[l * 64 + o];
                    if (l == 0) // h1 handoff (both q2 halves write identical bits)
                        sH[b][d * HT_STRIDE + o] = f2bf(v);
                }
            }
        }
    }

    // each (o,d) accumulated by both q2 halves -> halve at the end
    contrib0 *= 0.5f;
    contrib1 *= 0.5f;
#pragma unroll
    for (int off = 32; off > 0; off >>= 1) {
        contrib0 += __shfl_down(contrib0, off, 64);
        contrib1 += __shfl_down(contrib1, off, 64);
    }
    if (lane == 0) { sRed[w][0] = contrib0; sRed[w][1] = contrib1; }
    __syncthreads();
    if (tid < 2)
        out[bb * 2 + tid] = sRed[0][tid] + sRed[1][tid] + sRed[2][tid] + sRed[3][tid] + bfc[0];
}

extern "C" void kernel_launch(void* const* d_in, const int* in_sizes, int n_in,
                              void* d_out, int out_size, void* d_ws, size_t ws_size,
                              hipStream_t stream) {
    const float* x = (const float*)d_in[0];
    const float* W1 = (const float*)d_in[1];
    const float* b1 = (const float*)d_in[2];
    const float* W2 = (const float*)d_in[3];
    const float* b2 = (const float*)d_in[4];
    const float* Wfc = (const float*)d_in[5];
    const float* bfc = (const float*)d_in[6];
    float* out = (float*)d_out;

    unsigned short* Wp = (unsigned short*)d_ws; // 524288 bf16 = 1 MB prepacked W'

    prepack_kernel<<<128, 256, 0, stream>>>(W1, W2, Wp);
    cin_kernel<<<512, 256, 0, stream>>>(x, Wp, b1, b2, Wfc, bfc, out);
}